// Round 2
// baseline (12944.684 us; speedup 1.0000x reference)
//
#include <hip/hip_runtime.h>
#include <cstddef>

namespace {

constexpr int H = 4, D = 32, HID = 128;
constexpr int NA = 100000, NW = 20000, NO = 50000;
constexpr int NTOT = NA + NW + NO;
constexpr int E = 150000;
constexpr float SCALE = 0.17677669529663687f;  // 1/sqrt(32)

__device__ __forceinline__ float gelu_exact(float x) {
  return 0.5f * x * (1.f + erff(x * 0.7071067811865475f));
}

// order-preserving float->uint map for atomicMax (0 == below any encoded value)
__device__ __forceinline__ unsigned encodeF(float f) {
  unsigned u = __float_as_uint(f);
  return (u & 0x80000000u) ? ~u : (u | 0x80000000u);
}
__device__ __forceinline__ float decodeF(unsigned u) {
  return (u & 0x80000000u) ? __uint_as_float(u & 0x7FFFFFFFu)
                           : __uint_as_float(~u);
}

__device__ __forceinline__ unsigned short f2bf(float f) {  // RNE
  unsigned u = __float_as_uint(f);
  return (unsigned short)((u + 0x7FFF + ((u >> 16) & 1)) >> 16);
}

// load 32 contiguous bf16 (as ushort) -> 32 floats; p must be 16B-aligned
__device__ __forceinline__ void load32bf(const unsigned short* p, float* out) {
  const uint4* u4 = (const uint4*)p;
  #pragma unroll
  for (int i = 0; i < 4; i++) {
    uint4 u = u4[i];
    unsigned w[4] = {u.x, u.y, u.z, u.w};
    #pragma unroll
    for (int j = 0; j < 4; j++) {
      out[i * 8 + j * 2 + 0] = __uint_as_float(w[j] << 16);
      out[i * 8 + j * 2 + 1] = __uint_as_float(w[j] & 0xFFFF0000u);
    }
  }
}

// C(M, Ncols) = act_out( act_in(A(M,K)) @ W(K, Ncols slice, ld=ldw) + bias )
// C written with leading dim ldc; OUT_BF16 stores ushort-bf16.
template <bool GELU_A, bool RELU_OUT, bool OUT_BF16>
__global__ __launch_bounds__(256) void gemm_tiled(
    const float* __restrict__ A, const float* __restrict__ W,
    const float* __restrict__ bias, void* __restrict__ Cv,
    int M, int K, int ldw, int ldc) {
  __shared__ float As[32][68];
  __shared__ float Bs[32][68];
  const int tid = threadIdx.x;
  const int bm = blockIdx.x * 64;
  const int bn = blockIdx.y * 64;
  const int tx = tid & 15;
  const int ty = tid >> 4;
  float acc[4][4] = {};
  for (int kk = 0; kk < K; kk += 32) {
    #pragma unroll
    for (int i = 0; i < 8; i++) {
      int idx = tid + i * 256;
      int c = idx & 31, r = idx >> 5;
      int gr = bm + r;
      float v = 0.f;
      if (gr < M) v = A[(size_t)gr * K + kk + c];
      if (GELU_A) v = gelu_exact(v);
      As[c][r] = v;
    }
    #pragma unroll
    for (int i = 0; i < 8; i++) {
      int idx = tid + i * 256;
      int c = idx & 63, r = idx >> 6;
      Bs[r][c] = W[(size_t)(kk + r) * ldw + bn + c];
    }
    __syncthreads();
    #pragma unroll
    for (int k = 0; k < 32; k++) {
      const float4 a4 = *(const float4*)&As[k][ty * 4];
      const float4 b4 = *(const float4*)&Bs[k][tx * 4];
      float av[4] = {a4.x, a4.y, a4.z, a4.w};
      float bv[4] = {b4.x, b4.y, b4.z, b4.w};
      #pragma unroll
      for (int i = 0; i < 4; i++)
        #pragma unroll
        for (int j = 0; j < 4; j++) acc[i][j] += av[i] * bv[j];
    }
    __syncthreads();
  }
  const float4 bb = *(const float4*)&bias[bn + tx * 4];
  float bv[4] = {bb.x, bb.y, bb.z, bb.w};
  #pragma unroll
  for (int i = 0; i < 4; i++) {
    int gr = bm + ty * 4 + i;
    if (gr >= M) continue;
    float o[4];
    #pragma unroll
    for (int j = 0; j < 4; j++) {
      o[j] = acc[i][j] + bv[j];
      if (RELU_OUT) o[j] = fmaxf(o[j], 0.f);
    }
    if (OUT_BF16) {
      ushort4 s;
      s.x = f2bf(o[0]); s.y = f2bf(o[1]); s.z = f2bf(o[2]); s.w = f2bf(o[3]);
      *(ushort4*)&((unsigned short*)Cv)[(size_t)gr * ldc + bn + tx * 4] = s;
    } else {
      float4 v;
      v.x = o[0]; v.y = o[1]; v.z = o[2]; v.w = o[3];
      *(float4*)&((float*)Cv)[(size_t)gr * ldc + bn + tx * 4] = v;
    }
  }
}

// fused: xs = relu(LN( g*(gelu(A) @ W_o + b_o) + (1-g)*xs ))
// tile 64 rows x 128 cols (full row per block) so LN fits in-block.
__global__ __launch_bounds__(256) void gemm_wo_ln(
    const float* __restrict__ A, const float* __restrict__ W,
    const float* __restrict__ bias, float* __restrict__ xs,
    const float* __restrict__ skip_p, const float* __restrict__ g_ln,
    const float* __restrict__ b_ln, int M) {
  __shared__ float As[32][68];
  __shared__ float Bs[32][132];
  const int tid = threadIdx.x;
  const int bm = blockIdx.x * 64;
  const int tx = tid & 15;   // 8 cols each
  const int ty = tid >> 4;   // 4 rows each
  float acc[4][8] = {};
  for (int kk = 0; kk < HID; kk += 32) {
    #pragma unroll
    for (int i = 0; i < 8; i++) {
      int idx = tid + i * 256;
      int c = idx & 31, r = idx >> 5;
      int gr = bm + r;
      float v = 0.f;
      if (gr < M) v = gelu_exact(A[(size_t)gr * HID + kk + c]);
      As[c][r] = v;
    }
    #pragma unroll
    for (int i = 0; i < 16; i++) {
      int idx = tid + i * 256;
      int c = idx & 127, r = idx >> 7;
      Bs[r][c] = W[(size_t)(kk + r) * HID + c];
    }
    __syncthreads();
    #pragma unroll
    for (int k = 0; k < 32; k++) {
      const float4 a4 = *(const float4*)&As[k][ty * 4];
      const float4 b0 = *(const float4*)&Bs[k][tx * 8];
      const float4 b1 = *(const float4*)&Bs[k][tx * 8 + 4];
      float av[4] = {a4.x, a4.y, a4.z, a4.w};
      float bv[8] = {b0.x, b0.y, b0.z, b0.w, b1.x, b1.y, b1.z, b1.w};
      #pragma unroll
      for (int i = 0; i < 4; i++)
        #pragma unroll
        for (int j = 0; j < 8; j++) acc[i][j] += av[i] * bv[j];
    }
    __syncthreads();
  }
  const float g = 1.f / (1.f + expf(-skip_p[0]));
  float bb[8], gl[8], bl[8];
  #pragma unroll
  for (int j = 0; j < 8; j++) {
    bb[j] = bias[tx * 8 + j];
    gl[j] = g_ln[tx * 8 + j];
    bl[j] = b_ln[tx * 8 + j];
  }
  #pragma unroll
  for (int i = 0; i < 4; i++) {
    int gr = bm + ty * 4 + i;
    bool ok = gr < M;
    float xold[8] = {};
    if (ok) {
      const float4 x0 = *(const float4*)&xs[(size_t)gr * HID + tx * 8];
      const float4 x1 = *(const float4*)&xs[(size_t)gr * HID + tx * 8 + 4];
      xold[0] = x0.x; xold[1] = x0.y; xold[2] = x0.z; xold[3] = x0.w;
      xold[4] = x1.x; xold[5] = x1.y; xold[6] = x1.z; xold[7] = x1.w;
    }
    float v[8];
    float sum = 0.f, sq = 0.f;
    #pragma unroll
    for (int j = 0; j < 8; j++) {
      v[j] = g * (acc[i][j] + bb[j]) + (1.f - g) * xold[j];
      sum += v[j];
      sq += v[j] * v[j];
    }
    #pragma unroll
    for (int m = 1; m < 16; m <<= 1) {  // reduce across the 16 tx lanes
      sum += __shfl_xor(sum, m, 64);
      sq += __shfl_xor(sq, m, 64);
    }
    float mu = sum * (1.f / 128.f);
    float var = sq * (1.f / 128.f) - mu * mu;
    float r = rsqrtf(var + 1e-5f);
    if (ok) {
      float y[8];
      #pragma unroll
      for (int j = 0; j < 8; j++)
        y[j] = fmaxf((v[j] - mu) * r * gl[j] + bl[j], 0.f);
      float4 o0, o1;
      o0.x = y[0]; o0.y = y[1]; o0.z = y[2]; o0.w = y[3];
      o1.x = y[4]; o1.y = y[5]; o1.z = y[6]; o1.w = y[7];
      *(float4*)&xs[(size_t)gr * HID + tx * 8] = o0;
      *(float4*)&xs[(size_t)gr * HID + tx * 8 + 4] = o1;
    }
  }
}

// pass 1: alpha = (q_dst . (k_src @ a_rel[h])) * p * scale ; atomicMax per-dst
__global__ __launch_bounds__(256) void edge_alpha(
    const unsigned short* __restrict__ kbuf, const float* __restrict__ qbuf,
    const int* __restrict__ src, const int* __restrict__ dst,
    const float* __restrict__ arel, const float* __restrict__ prel,
    float* __restrict__ alphaOut, unsigned* __restrict__ amax, int srcOff,
    int dstOff) {
  int idx = blockIdx.x * 256 + threadIdx.x;
  if (idx >= E * H) return;
  int e = idx >> 2, h = idx & 3;
  int s = src[e], dd = dst[e];
  float kk[32], qq[32];
  load32bf(kbuf + (size_t)(srcOff + s) * HID + h * 32, kk);
  {
    const float4* q4 = (const float4*)(qbuf + (size_t)(dstOff + dd) * HID + h * 32);
    #pragma unroll
    for (int j = 0; j < 8; j++) {
      float4 b = q4[j];
      qq[j * 4 + 0] = b.x; qq[j * 4 + 1] = b.y;
      qq[j * 4 + 2] = b.z; qq[j * 4 + 3] = b.w;
    }
  }
  const float* Ar = arel + h * D * D;
  float acc = 0.f;
  #pragma unroll 8
  for (int d2 = 0; d2 < 32; d2++) {
    float kd = kk[d2];
    const float4* row = (const float4*)(Ar + d2 * 32);
    #pragma unroll
    for (int j = 0; j < 8; j++) {
      float4 a4 = row[j];
      acc += kd * (a4.x * qq[j * 4] + a4.y * qq[j * 4 + 1] +
                   a4.z * qq[j * 4 + 2] + a4.w * qq[j * 4 + 3]);
    }
  }
  acc *= prel[h] * SCALE;
  alphaOut[idx] = acc;
  atomicMax(&amax[(size_t)(dstOff + dd) * H + h], encodeF(acc));
}

// pass 2: ex = exp(alpha - max); den += ex
__global__ __launch_bounds__(256) void edge_ex(
    float* __restrict__ alphaB, const int* __restrict__ dst,
    const unsigned* __restrict__ amax, float* __restrict__ den, int dstOff) {
  int idx = blockIdx.x * 256 + threadIdx.x;
  if (idx >= E * H) return;
  int e = idx >> 2, h = idx & 3;
  int dg = dstOff + dst[e];
  float m = decodeF(amax[(size_t)dg * H + h]);
  float ex = expf(alphaB[idx] - m);
  alphaB[idx] = ex;
  atomicAdd(&den[(size_t)dg * H + h], ex);
}

// pass 3: w = ex/den; agg[dst] += w * (v_src @ m_rel[h])
__global__ __launch_bounds__(256) void edge_agg(
    const unsigned short* __restrict__ vbuf, const float* __restrict__ exB,
    const int* __restrict__ src, const int* __restrict__ dst,
    const float* __restrict__ mrel, const float* __restrict__ den,
    float* __restrict__ agg, int srcOff, int dstOff) {
  int idx = blockIdx.x * 256 + threadIdx.x;
  if (idx >= E * H) return;
  int e = idx >> 2, h = idx & 3;
  int dg = dstOff + dst[e];
  float w = exB[idx] / (den[(size_t)dg * H + h] + 1e-16f);
  float vv[32];
  load32bf(vbuf + (size_t)(srcOff + src[e]) * HID + h * 32, vv);
  const float* Mr = mrel + h * D * D;
  float ve[32] = {};
  #pragma unroll 8
  for (int d2 = 0; d2 < 32; d2++) {
    float vd = vv[d2];
    const float4* row = (const float4*)(Mr + d2 * 32);
    #pragma unroll
    for (int j = 0; j < 8; j++) {
      float4 a4 = row[j];
      ve[j * 4 + 0] += vd * a4.x; ve[j * 4 + 1] += vd * a4.y;
      ve[j * 4 + 2] += vd * a4.z; ve[j * 4 + 3] += vd * a4.w;
    }
  }
  float* out = agg + (size_t)dg * HID + h * 32;
  #pragma unroll
  for (int j = 0; j < 32; j++) atomicAdd(out + j, w * ve[j]);
}

__global__ __launch_bounds__(256) void head_kernel(
    const float* __restrict__ xs0, const float* __restrict__ w_head,
    const float* __restrict__ b_head, const float* __restrict__ basep,
    float* __restrict__ out, int Nrows) {
  int wid = (blockIdx.x * 256 + threadIdx.x) >> 6;
  int lane = threadIdx.x & 63;
  if (wid >= Nrows) return;
  size_t base = (size_t)wid * HID;
  float d = xs0[base + lane] * w_head[lane] +
            xs0[base + 64 + lane] * w_head[64 + lane];
  #pragma unroll
  for (int m = 1; m < 64; m <<= 1) d += __shfl_xor(d, m, 64);
  if (lane == 0) out[wid] = basep[0] + b_head[0] + d;
}

}  // namespace

extern "C" void kernel_launch(void* const* d_in, const int* in_sizes, int n_in,
                              void* d_out, int out_size, void* d_ws,
                              size_t ws_size, hipStream_t stream) {
  const float* x_a = (const float*)d_in[0];
  const float* x_w = (const float*)d_in[1];
  const float* x_o = (const float*)d_in[2];
  const float* W_in = (const float*)d_in[3];
  const float* b_in = (const float*)d_in[4];
  const float* W_kqv = (const float*)d_in[5];
  const float* b_kqv = (const float*)d_in[6];
  const float* a_rel = (const float*)d_in[7];
  const float* m_rel = (const float*)d_in[8];
  const float* p_rel = (const float*)d_in[9];
  const float* skip_p = (const float*)d_in[10];
  const float* W_o = (const float*)d_in[11];
  const float* b_o = (const float*)d_in[12];
  const float* ln_g = (const float*)d_in[13];
  const float* ln_b = (const float*)d_in[14];
  const float* w_head = (const float*)d_in[15];
  const float* b_head = (const float*)d_in[16];
  const float* basep = (const float*)d_in[17];
  const int* srcs[4] = {(const int*)d_in[18], (const int*)d_in[20],
                        (const int*)d_in[22], (const int*)d_in[24]};
  const int* dsts[4] = {(const int*)d_in[19], (const int*)d_in[21],
                        (const int*)d_in[23], (const int*)d_in[25]};
  const int est[4] = {1, 2, 0, 0}, edt[4] = {0, 0, 1, 2};
  const int OFF[4] = {0, NA, NA + NW, NTOT};
  const int NT[3] = {NA, NW, NO};
  const float* xin[3] = {x_a, x_w, x_o};

  // compact workspace layout (peak ~222 MiB):
  //   xs      fp32  NTOT*128           (87.0 MB)  persistent per layer
  //   kv      bf16  NTOT*128           (43.5 MB)  k during alpha, then v
  //   qagg    fp32  NTOT*128           (87.0 MB)  q during alpha, then agg
  //   alpha   fp32  4*E*H              ( 9.6 MB)
  //   amax    u32   NTOT*H             ( 2.7 MB)
  //   den     fp32  NTOT*H             ( 2.7 MB)
  const size_t SZ_XS = (size_t)NTOT * HID * 4;
  const size_t SZ_KV = (size_t)NTOT * HID * 2;
  const size_t SZ_QA = (size_t)NTOT * HID * 4;
  const size_t SZ_AL = (size_t)4 * E * H * 4;
  const size_t SZ_AM = (size_t)NTOT * H * 4;
  const size_t need = SZ_XS + SZ_KV + SZ_QA + SZ_AL + 2 * SZ_AM;
  if (ws_size < need) return;  // diagnostic: clean absmax-fail, not a fault

  char* p = (char*)d_ws;
  float* xs = (float*)p;            p += SZ_XS;
  unsigned short* kv = (unsigned short*)p; p += SZ_KV;
  float* qagg = (float*)p;          p += SZ_QA;
  float* alphaB = (float*)p;        p += SZ_AL;
  unsigned* amaxB = (unsigned*)p;   p += SZ_AM;
  float* denB = (float*)p;

  // input projection: xs[t] = relu(x @ W_in[t] + b_in[t])
  for (int t = 0; t < 3; t++) {
    dim3 g((NT[t] + 63) / 64, 2);
    gemm_tiled<false, true, false><<<g, 256, 0, stream>>>(
        xin[t], W_in + (size_t)t * 64 * HID, b_in + t * HID,
        xs + (size_t)OFF[t] * HID, NT[t], 64, HID, HID);
  }

  const int eb = (E * H + 255) / 256;
  for (int l = 0; l < 2; l++) {
    for (int t = 0; t < 3; t++) {
      const float* Wk = W_kqv + (size_t)(l * 3 + t) * HID * 3 * HID;
      const float* bk = b_kqv + (size_t)(l * 3 + t) * 3 * HID;
      dim3 g((NT[t] + 63) / 64, 2);
      // k -> kv (bf16)
      gemm_tiled<false, false, true><<<g, 256, 0, stream>>>(
          xs + (size_t)OFF[t] * HID, Wk, bk, kv + (size_t)OFF[t] * HID,
          NT[t], HID, 3 * HID, HID);
      // q -> qagg (fp32)
      gemm_tiled<false, false, false><<<g, 256, 0, stream>>>(
          xs + (size_t)OFF[t] * HID, Wk + HID, bk + HID,
          qagg + (size_t)OFF[t] * HID, NT[t], HID, 3 * HID, HID);
    }
    hipMemsetAsync(amaxB, 0, SZ_AM, stream);  // 0 == encoded "-inf"
    hipMemsetAsync(denB, 0, SZ_AM, stream);
    for (int et = 0; et < 4; et++)
      edge_alpha<<<eb, 256, 0, stream>>>(
          kv, qagg, srcs[et], dsts[et],
          a_rel + (size_t)(l * 4 + et) * H * D * D,
          p_rel + (size_t)(l * 4 + et) * H, alphaB + (size_t)et * E * H, amaxB,
          OFF[est[et]], OFF[edt[et]]);
    for (int et = 0; et < 4; et++)
      edge_ex<<<eb, 256, 0, stream>>>(alphaB + (size_t)et * E * H, dsts[et],
                                      amaxB, denB, OFF[edt[et]]);
    // v -> kv (bf16), overwriting k (dead after alpha pass)
    for (int t = 0; t < 3; t++) {
      const float* Wk = W_kqv + (size_t)(l * 3 + t) * HID * 3 * HID;
      const float* bk = b_kqv + (size_t)(l * 3 + t) * 3 * HID;
      dim3 g((NT[t] + 63) / 64, 2);
      gemm_tiled<false, false, true><<<g, 256, 0, stream>>>(
          xs + (size_t)OFF[t] * HID, Wk + 2 * HID, bk + 2 * HID,
          kv + (size_t)OFF[t] * HID, NT[t], HID, 3 * HID, HID);
    }
    // agg (aliases q, dead after alpha pass)
    hipMemsetAsync(qagg, 0, SZ_QA, stream);
    for (int et = 0; et < 4; et++)
      edge_agg<<<eb, 256, 0, stream>>>(
          kv, alphaB + (size_t)et * E * H, srcs[et], dsts[et],
          m_rel + (size_t)(l * 4 + et) * H * D * D, denB, qagg, OFF[est[et]],
          OFF[edt[et]]);
    // fused: xs = relu(LN(g*(gelu(agg) @ W_o + b_o) + (1-g)*xs))
    for (int t = 0; t < 3; t++) {
      int blocks = (NT[t] + 63) / 64;
      gemm_wo_ln<<<blocks, 256, 0, stream>>>(
          qagg + (size_t)OFF[t] * HID, W_o + (size_t)(l * 3 + t) * HID * HID,
          b_o + (size_t)(l * 3 + t) * HID, xs + (size_t)OFF[t] * HID,
          skip_p + l * 3 + t, ln_g + (size_t)(l * 3 + t) * HID,
          ln_b + (size_t)(l * 3 + t) * HID, NT[t]);
    }
  }
  head_kernel<<<(NA + 3) / 4, 256, 0, stream>>>(xs, w_head, b_head, basep,
                                                (float*)d_out, NA);
}

// Round 3
// 3583.456 us; speedup vs baseline: 3.6123x; 3.6123x over previous
//
#include <hip/hip_runtime.h>
#include <cstddef>
#include <cmath>

namespace {

constexpr int H = 4, D = 32, HID = 128;
constexpr int NA = 100000, NW = 20000, NO = 50000;
constexpr int NTOT = NA + NW + NO;
constexpr int E = 150000;
constexpr float SCALE = 0.17677669529663687f;  // 1/sqrt(32)

__device__ __forceinline__ float gelu_exact(float x) {
  return 0.5f * x * (1.f + erff(x * 0.7071067811865475f));
}

__device__ __forceinline__ unsigned short f2bf(float f) {  // RNE
  unsigned u = __float_as_uint(f);
  return (unsigned short)((u + 0x7FFF + ((u >> 16) & 1)) >> 16);
}
__device__ __forceinline__ float bf2f(unsigned short s) {
  return __uint_as_float(((unsigned)s) << 16);
}
__device__ __forceinline__ unsigned pack2(float lo, float hi) {
  return (unsigned)f2bf(lo) | ((unsigned)f2bf(hi) << 16);
}

// load 32 contiguous bf16 (as ushort) -> 32 floats; p must be 16B-aligned
__device__ __forceinline__ void load32bf(const unsigned short* p, float* out) {
  const uint4* u4 = (const uint4*)p;
  #pragma unroll
  for (int i = 0; i < 4; i++) {
    uint4 u = u4[i];
    unsigned w[4] = {u.x, u.y, u.z, u.w};
    #pragma unroll
    for (int j = 0; j < 4; j++) {
      out[i * 8 + j * 2 + 0] = __uint_as_float(w[j] << 16);
      out[i * 8 + j * 2 + 1] = __uint_as_float(w[j] & 0xFFFF0000u);
    }
  }
}

// ---------------- GEMM (fp32 compute) ----------------
// C(M, 64-col tile) = act_out( A(M,K) @ W(K, ld=ldw) + bias )
template <bool RELU_OUT, bool OUT_BF16>
__global__ __launch_bounds__(256) void gemm_tiled(
    const float* __restrict__ A, const float* __restrict__ W,
    const float* __restrict__ bias, void* __restrict__ Cv,
    int M, int K, int ldw, int ldc) {
  __shared__ float As[32][68];
  __shared__ float Bs[32][68];
  const int tid = threadIdx.x;
  const int bm = blockIdx.x * 64;
  const int bn = blockIdx.y * 64;
  const int tx = tid & 15;
  const int ty = tid >> 4;
  float acc[4][4] = {};
  for (int kk = 0; kk < K; kk += 32) {
    #pragma unroll
    for (int i = 0; i < 8; i++) {
      int idx = tid + i * 256;
      int c = idx & 31, r = idx >> 5;
      int gr = bm + r;
      float v = 0.f;
      if (gr < M) v = A[(size_t)gr * K + kk + c];
      As[c][r] = v;
    }
    #pragma unroll
    for (int i = 0; i < 8; i++) {
      int idx = tid + i * 256;
      int c = idx & 63, r = idx >> 6;
      Bs[r][c] = W[(size_t)(kk + r) * ldw + bn + c];
    }
    __syncthreads();
    #pragma unroll
    for (int k = 0; k < 32; k++) {
      const float4 a4 = *(const float4*)&As[k][ty * 4];
      const float4 b4 = *(const float4*)&Bs[k][tx * 4];
      float av[4] = {a4.x, a4.y, a4.z, a4.w};
      float bv[4] = {b4.x, b4.y, b4.z, b4.w};
      #pragma unroll
      for (int i = 0; i < 4; i++)
        #pragma unroll
        for (int j = 0; j < 4; j++) acc[i][j] += av[i] * bv[j];
    }
    __syncthreads();
  }
  const float4 bb = *(const float4*)&bias[bn + tx * 4];
  float bv[4] = {bb.x, bb.y, bb.z, bb.w};
  #pragma unroll
  for (int i = 0; i < 4; i++) {
    int gr = bm + ty * 4 + i;
    if (gr >= M) continue;
    float o[4];
    #pragma unroll
    for (int j = 0; j < 4; j++) {
      o[j] = acc[i][j] + bv[j];
      if (RELU_OUT) o[j] = fmaxf(o[j], 0.f);
    }
    if (OUT_BF16) {
      ushort4 s;
      s.x = f2bf(o[0]); s.y = f2bf(o[1]); s.z = f2bf(o[2]); s.w = f2bf(o[3]);
      *(ushort4*)&((unsigned short*)Cv)[(size_t)gr * ldc + bn + tx * 4] = s;
    } else {
      float4 v;
      v.x = o[0]; v.y = o[1]; v.z = o[2]; v.w = o[3];
      *(float4*)&((float*)Cv)[(size_t)gr * ldc + bn + tx * 4] = v;
    }
  }
}

// fused: xs = relu(LN( g*(gelu(A_bf16) @ W_o + b_o) + (1-g)*xs ))
__global__ __launch_bounds__(256) void gemm_wo_ln(
    const unsigned short* __restrict__ A, const float* __restrict__ W,
    const float* __restrict__ bias, float* __restrict__ xs,
    const float* __restrict__ skip_p, const float* __restrict__ g_ln,
    const float* __restrict__ b_ln, int M) {
  __shared__ float As[32][68];
  __shared__ float Bs[32][132];
  const int tid = threadIdx.x;
  const int bm = blockIdx.x * 64;
  const int tx = tid & 15;   // 8 cols each
  const int ty = tid >> 4;   // 4 rows each
  float acc[4][8] = {};
  for (int kk = 0; kk < HID; kk += 32) {
    #pragma unroll
    for (int i = 0; i < 8; i++) {
      int idx = tid + i * 256;
      int c = idx & 31, r = idx >> 5;
      int gr = bm + r;
      float v = 0.f;
      if (gr < M) v = gelu_exact(bf2f(A[(size_t)gr * HID + kk + c]));
      As[c][r] = v;
    }
    #pragma unroll
    for (int i = 0; i < 16; i++) {
      int idx = tid + i * 256;
      int c = idx & 127, r = idx >> 7;
      Bs[r][c] = W[(size_t)(kk + r) * HID + c];
    }
    __syncthreads();
    #pragma unroll
    for (int k = 0; k < 32; k++) {
      const float4 a4 = *(const float4*)&As[k][ty * 4];
      const float4 b0 = *(const float4*)&Bs[k][tx * 8];
      const float4 b1 = *(const float4*)&Bs[k][tx * 8 + 4];
      float av[4] = {a4.x, a4.y, a4.z, a4.w};
      float bv[8] = {b0.x, b0.y, b0.z, b0.w, b1.x, b1.y, b1.z, b1.w};
      #pragma unroll
      for (int i = 0; i < 4; i++)
        #pragma unroll
        for (int j = 0; j < 8; j++) acc[i][j] += av[i] * bv[j];
    }
    __syncthreads();
  }
  const float g = 1.f / (1.f + expf(-skip_p[0]));
  float bb[8], gl[8], bl[8];
  #pragma unroll
  for (int j = 0; j < 8; j++) {
    bb[j] = bias[tx * 8 + j];
    gl[j] = g_ln[tx * 8 + j];
    bl[j] = b_ln[tx * 8 + j];
  }
  #pragma unroll
  for (int i = 0; i < 4; i++) {
    int gr = bm + ty * 4 + i;
    bool ok = gr < M;
    float xold[8] = {};
    if (ok) {
      const float4 x0 = *(const float4*)&xs[(size_t)gr * HID + tx * 8];
      const float4 x1 = *(const float4*)&xs[(size_t)gr * HID + tx * 8 + 4];
      xold[0] = x0.x; xold[1] = x0.y; xold[2] = x0.z; xold[3] = x0.w;
      xold[4] = x1.x; xold[5] = x1.y; xold[6] = x1.z; xold[7] = x1.w;
    }
    float v[8];
    float sum = 0.f, sq = 0.f;
    #pragma unroll
    for (int j = 0; j < 8; j++) {
      v[j] = g * (acc[i][j] + bb[j]) + (1.f - g) * xold[j];
      sum += v[j];
      sq += v[j] * v[j];
    }
    #pragma unroll
    for (int m = 1; m < 16; m <<= 1) {
      sum += __shfl_xor(sum, m, 64);
      sq += __shfl_xor(sq, m, 64);
    }
    float mu = sum * (1.f / 128.f);
    float var = sq * (1.f / 128.f) - mu * mu;
    float r = rsqrtf(var + 1e-5f);
    if (ok) {
      float y[8];
      #pragma unroll
      for (int j = 0; j < 8; j++)
        y[j] = fmaxf((v[j] - mu) * r * gl[j] + bl[j], 0.f);
      float4 o0, o1;
      o0.x = y[0]; o0.y = y[1]; o0.z = y[2]; o0.w = y[3];
      o1.x = y[4]; o1.y = y[5]; o1.z = y[6]; o1.w = y[7];
      *(float4*)&xs[(size_t)gr * HID + tx * 8] = o0;
      *(float4*)&xs[(size_t)gr * HID + tx * 8 + 4] = o1;
    }
  }
}

// ---------------- CSR build (deterministic) ----------------
__global__ __launch_bounds__(256) void csr_hist(const int* __restrict__ dst,
                                                int* __restrict__ cnt, int n) {
  int e = blockIdx.x * 256 + threadIdx.x;
  if (e < n) atomicAdd(&cnt[dst[e]], 1);
}

// per-256-block exclusive scan; block totals to bsum
__global__ __launch_bounds__(256) void scan_block(const int* __restrict__ cnt,
                                                  int* __restrict__ excl,
                                                  int* __restrict__ bsum,
                                                  int n) {
  __shared__ int tmp[256];
  int i = blockIdx.x * 256 + threadIdx.x;
  int v = (i < n) ? cnt[i] : 0;
  tmp[threadIdx.x] = v;
  __syncthreads();
  int acc = v;
  for (int off = 1; off < 256; off <<= 1) {
    int other = (threadIdx.x >= off) ? tmp[threadIdx.x - off] : 0;
    __syncthreads();
    acc += other;
    tmp[threadIdx.x] = acc;
    __syncthreads();
  }
  if (i < n) excl[i] = acc - v;
  if (threadIdx.x == 255) bsum[blockIdx.x] = acc;
}

// single-block exclusive scan of bsum (chunked with carry)
__global__ __launch_bounds__(256) void scan_bsums(int* __restrict__ bsum,
                                                  int nb) {
  __shared__ int tmp[256];
  __shared__ int carry;
  if (threadIdx.x == 0) carry = 0;
  __syncthreads();
  for (int start = 0; start < nb; start += 256) {
    int i = start + threadIdx.x;
    int v = (i < nb) ? bsum[i] : 0;
    tmp[threadIdx.x] = v;
    __syncthreads();
    int acc = v;
    for (int off = 1; off < 256; off <<= 1) {
      int other = (threadIdx.x >= off) ? tmp[threadIdx.x - off] : 0;
      __syncthreads();
      acc += other;
      tmp[threadIdx.x] = acc;
      __syncthreads();
    }
    int c = carry;
    if (i < nb) bsum[i] = c + acc - v;
    __syncthreads();
    if (threadIdx.x == 255) carry = c + acc;
    __syncthreads();
  }
}

__global__ __launch_bounds__(256) void csr_finalize(int* __restrict__ rp,
                                                    const int* __restrict__ bsum,
                                                    int* __restrict__ cursor,
                                                    int n, int ne) {
  int i = blockIdx.x * 256 + threadIdx.x;
  if (i < n) {
    int v = rp[i] + bsum[i >> 8];
    rp[i] = v;
    cursor[i] = v;
  } else if (i == n) {
    rp[n] = ne;
  }
}

__global__ __launch_bounds__(256) void csr_scatter(const int* __restrict__ dst,
                                                   int* __restrict__ cursor,
                                                   int* __restrict__ ce, int n) {
  int e = blockIdx.x * 256 + threadIdx.x;
  if (e < n) {
    int slot = atomicAdd(&cursor[dst[e]], 1);
    ce[slot] = e;
  }
}

// canonicalize each dst's edge list (ascending) -> deterministic fp order
__global__ __launch_bounds__(256) void csr_sort(const int* __restrict__ rp,
                                                int* __restrict__ ce, int n) {
  int d = blockIdx.x * 256 + threadIdx.x;
  if (d >= n) return;
  int b = rp[d], e = rp[d + 1];
  for (int i = b + 1; i < e; i++) {
    int key = ce[i];
    int j = i - 1;
    while (j >= b && ce[j] > key) { ce[j + 1] = ce[j]; j--; }
    ce[j + 1] = key;
  }
}

// ---------------- gather attention ----------------
// thread = (dstLocal, h). alpha = k_src . (A @ q_dst) * p * scale
// online max/sum; store raw alpha per csr slot; store per-(dst,h) m, den.
__global__ __launch_bounds__(256) void alpha_gather(
    const unsigned short* __restrict__ kbuf,
    const unsigned short* __restrict__ qbuf, const int* __restrict__ rp0,
    const int* __restrict__ ce0, const int* __restrict__ src0,
    const float* __restrict__ A0, const float* __restrict__ p0,
    float* __restrict__ alpha0, const int* __restrict__ rp1,
    const int* __restrict__ ce1, const int* __restrict__ src1,
    const float* __restrict__ A1, const float* __restrict__ p1,
    float* __restrict__ alpha1, int net, int srcOff0, int srcOff1, int dstOff,
    int Ndst, float* __restrict__ maxB, float* __restrict__ denB) {
  int t = blockIdx.x * 256 + threadIdx.x;
  if (t >= Ndst * H) return;
  int dl = t >> 2, h = t & 3;
  float qv[32];
  load32bf(qbuf + (size_t)(dstOff + dl) * HID + h * 32, qv);
  float mx = -INFINITY, den = 0.f;
  for (int s = 0; s < net; s++) {
    const int* rp = s ? rp1 : rp0;
    const int* ce = s ? ce1 : ce0;
    const int* src = s ? src1 : src0;
    const float* A = (s ? A1 : A0) + h * D * D;
    float pr = (s ? p1 : p0)[h] * SCALE;
    float* alphaO = s ? alpha1 : alpha0;
    int srcOff = s ? srcOff1 : srcOff0;
    // qA[d] = sum_e A[d][e] * q[e]
    float qA[32];
    #pragma unroll 4
    for (int d2 = 0; d2 < 32; d2++) {
      const float4* r4 = (const float4*)(A + d2 * 32);
      float a = 0.f;
      #pragma unroll
      for (int j = 0; j < 8; j++) {
        float4 w = r4[j];
        a += w.x * qv[j * 4] + w.y * qv[j * 4 + 1] + w.z * qv[j * 4 + 2] +
             w.w * qv[j * 4 + 3];
      }
      qA[d2] = a;
    }
    int b = rp[dl], en = rp[dl + 1];
    for (int i = b; i < en; i++) {
      int e = ce[i];
      float kv[32];
      load32bf(kbuf + (size_t)(srcOff + src[e]) * HID + h * 32, kv);
      float a = 0.f;
      #pragma unroll
      for (int j = 0; j < 32; j++) a += qA[j] * kv[j];
      a *= pr;
      alphaO[(size_t)i * H + h] = a;
      float nm = fmaxf(mx, a);
      den = den * expf(mx - nm) + expf(a - nm);
      mx = nm;
    }
  }
  maxB[(size_t)(dstOff + dl) * H + h] = mx;
  denB[(size_t)(dstOff + dl) * H + h] = den;
}

// thread = (dstLocal, h). s = sum_e exp(alpha-m) * v_src ; agg = (s @ M)/den
__global__ __launch_bounds__(256) void agg_gather(
    const unsigned short* __restrict__ vbuf, const int* __restrict__ rp0,
    const int* __restrict__ ce0, const int* __restrict__ src0,
    const float* __restrict__ M0, const float* __restrict__ alpha0,
    const int* __restrict__ rp1, const int* __restrict__ ce1,
    const int* __restrict__ src1, const float* __restrict__ M1,
    const float* __restrict__ alpha1, int net, int srcOff0, int srcOff1,
    int dstOff, int Ndst, const float* __restrict__ maxB,
    const float* __restrict__ denB, unsigned short* __restrict__ agg) {
  int t = blockIdx.x * 256 + threadIdx.x;
  if (t >= Ndst * H) return;
  int dl = t >> 2, h = t & 3;
  float mx = maxB[(size_t)(dstOff + dl) * H + h];
  float inv = 1.f / (denB[(size_t)(dstOff + dl) * H + h] + 1e-16f);
  float acc[32] = {};
  for (int s = 0; s < net; s++) {
    const int* rp = s ? rp1 : rp0;
    const int* ce = s ? ce1 : ce0;
    const int* src = s ? src1 : src0;
    const float* M = (s ? M1 : M0) + h * D * D;
    const float* alphaI = s ? alpha1 : alpha0;
    int srcOff = s ? srcOff1 : srcOff0;
    float sv[32] = {};
    int b = rp[dl], en = rp[dl + 1];
    for (int i = b; i < en; i++) {
      int e = ce[i];
      float w = expf(alphaI[(size_t)i * H + h] - mx);
      float vv[32];
      load32bf(vbuf + (size_t)(srcOff + src[e]) * HID + h * 32, vv);
      #pragma unroll
      for (int j = 0; j < 32; j++) sv[j] += w * vv[j];
    }
    // acc[e] += sum_d sv[d] * M[d][e]
    #pragma unroll 4
    for (int d2 = 0; d2 < 32; d2++) {
      float sd = sv[d2];
      const float4* r4 = (const float4*)(M + d2 * 32);
      #pragma unroll
      for (int j = 0; j < 8; j++) {
        float4 w = r4[j];
        acc[j * 4 + 0] += sd * w.x; acc[j * 4 + 1] += sd * w.y;
        acc[j * 4 + 2] += sd * w.z; acc[j * 4 + 3] += sd * w.w;
      }
    }
  }
  unsigned short* out = agg + (size_t)(dstOff + dl) * HID + h * 32;
  #pragma unroll
  for (int i = 0; i < 4; i++) {
    uint4 w;
    w.x = pack2(acc[i * 8 + 0] * inv, acc[i * 8 + 1] * inv);
    w.y = pack2(acc[i * 8 + 2] * inv, acc[i * 8 + 3] * inv);
    w.z = pack2(acc[i * 8 + 4] * inv, acc[i * 8 + 5] * inv);
    w.w = pack2(acc[i * 8 + 6] * inv, acc[i * 8 + 7] * inv);
    *(uint4*)(out + i * 8) = w;
  }
}

__global__ __launch_bounds__(256) void head_kernel(
    const float* __restrict__ xs0, const float* __restrict__ w_head,
    const float* __restrict__ b_head, const float* __restrict__ basep,
    float* __restrict__ out, int Nrows) {
  int wid = (blockIdx.x * 256 + threadIdx.x) >> 6;
  int lane = threadIdx.x & 63;
  if (wid >= Nrows) return;
  size_t base = (size_t)wid * HID;
  float d = xs0[base + lane] * w_head[lane] +
            xs0[base + 64 + lane] * w_head[64 + lane];
  #pragma unroll
  for (int m = 1; m < 64; m <<= 1) d += __shfl_xor(d, m, 64);
  if (lane == 0) out[wid] = basep[0] + b_head[0] + d;
}

}  // namespace

extern "C" void kernel_launch(void* const* d_in, const int* in_sizes, int n_in,
                              void* d_out, int out_size, void* d_ws,
                              size_t ws_size, hipStream_t stream) {
  const float* x_a = (const float*)d_in[0];
  const float* x_w = (const float*)d_in[1];
  const float* x_o = (const float*)d_in[2];
  const float* W_in = (const float*)d_in[3];
  const float* b_in = (const float*)d_in[4];
  const float* W_kqv = (const float*)d_in[5];
  const float* b_kqv = (const float*)d_in[6];
  const float* a_rel = (const float*)d_in[7];
  const float* m_rel = (const float*)d_in[8];
  const float* p_rel = (const float*)d_in[9];
  const float* skip_p = (const float*)d_in[10];
  const float* W_o = (const float*)d_in[11];
  const float* b_o = (const float*)d_in[12];
  const float* ln_g = (const float*)d_in[13];
  const float* ln_b = (const float*)d_in[14];
  const float* w_head = (const float*)d_in[15];
  const float* b_head = (const float*)d_in[16];
  const float* basep = (const float*)d_in[17];
  const int* srcs[4] = {(const int*)d_in[18], (const int*)d_in[20],
                        (const int*)d_in[22], (const int*)d_in[24]};
  const int* dsts[4] = {(const int*)d_in[19], (const int*)d_in[21],
                        (const int*)d_in[23], (const int*)d_in[25]};
  const int OFF[4] = {0, NA, NA + NW, NTOT};
  const int NT[3] = {NA, NW, NO};
  const float* xin[3] = {x_a, x_w, x_o};

  // ---- workspace layout (~193 MB) ----
  const size_t SZ_XS = (size_t)NTOT * HID * 4;   // fp32 xs
  const size_t SZ_KV = (size_t)NTOT * HID * 2;   // bf16 k -> v
  const size_t SZ_QA = (size_t)NTOT * HID * 2;   // bf16 q -> agg
  const size_t SZ_AL = (size_t)4 * E * H * 4;    // fp32 raw alpha
  const size_t SZ_MD = (size_t)NTOT * H * 4;     // fp32 max / den
  const int RP_TOT = 2 * (NA + 1) + (NW + 1) + (NO + 1);  // 270004
  const size_t SZ_RP = ((size_t)RP_TOT * 4 + 63) & ~63ull;
  const size_t SZ_CE = (size_t)4 * E * 4;
  const size_t SZ_CU = ((size_t)(NA + 1) * 4 + 63) & ~63ull;
  const size_t SZ_BS = 512 * 4;
  const size_t need =
      SZ_XS + SZ_KV + SZ_QA + SZ_AL + 2 * SZ_MD + SZ_RP + SZ_CE + 2 * SZ_CU + SZ_BS;
  if (ws_size < need) return;

  char* p = (char*)d_ws;
  float* xs = (float*)p;                     p += SZ_XS;
  unsigned short* kv = (unsigned short*)p;   p += SZ_KV;
  unsigned short* qagg = (unsigned short*)p; p += SZ_QA;
  float* alphaB = (float*)p;                 p += SZ_AL;
  float* maxB = (float*)p;                   p += SZ_MD;
  float* denB = (float*)p;                   p += SZ_MD;
  int* rpAll = (int*)p;                      p += SZ_RP;
  int* ceAll = (int*)p;                      p += SZ_CE;
  int* cursor = (int*)p;                     p += SZ_CU;
  int* cnt = (int*)p;                        p += SZ_CU;
  int* bsum = (int*)p;

  const int rpOff[4] = {0, NA + 1, 2 * (NA + 1), 2 * (NA + 1) + NW + 1};
  const int NdstE[4] = {NA, NA, NW, NO};
  const int srcOffE[4] = {OFF[1], OFF[2], OFF[0], OFF[0]};
  const int eb = (E + 255) / 256;

  // ---- CSR build (once; edges shared by both layers) ----
  for (int et = 0; et < 4; et++) {
    int nd = NdstE[et];
    int* rp = rpAll + rpOff[et];
    int* ce = ceAll + (size_t)et * E;
    hipMemsetAsync(cnt, 0, (size_t)nd * 4, stream);
    csr_hist<<<eb, 256, 0, stream>>>(dsts[et], cnt, E);
    int nb = (nd + 255) / 256;
    scan_block<<<nb, 256, 0, stream>>>(cnt, rp, bsum, nd);
    scan_bsums<<<1, 256, 0, stream>>>(bsum, nb);
    csr_finalize<<<(nd + 256) / 256 + 1, 256, 0, stream>>>(rp, bsum, cursor,
                                                           nd, E);
    csr_scatter<<<eb, 256, 0, stream>>>(dsts[et], cursor, ce, E);
    csr_sort<<<(nd + 255) / 256, 256, 0, stream>>>(rp, ce, nd);
  }

  // ---- input projection: xs[t] = relu(x @ W_in[t] + b_in[t]) ----
  for (int t = 0; t < 3; t++) {
    dim3 g((NT[t] + 63) / 64, 2);
    gemm_tiled<true, false><<<g, 256, 0, stream>>>(
        xin[t], W_in + (size_t)t * 64 * HID, b_in + t * HID,
        xs + (size_t)OFF[t] * HID, NT[t], 64, HID, HID);
  }

  for (int l = 0; l < 2; l++) {
    const size_t DD = (size_t)H * D * D;
    // k -> kv (bf16), q -> qagg (bf16)
    for (int t = 0; t < 3; t++) {
      const float* Wk = W_kqv + (size_t)(l * 3 + t) * HID * 3 * HID;
      const float* bk = b_kqv + (size_t)(l * 3 + t) * 3 * HID;
      dim3 g((NT[t] + 63) / 64, 2);
      gemm_tiled<false, true><<<g, 256, 0, stream>>>(
          xs + (size_t)OFF[t] * HID, Wk, bk, kv + (size_t)OFF[t] * HID, NT[t],
          HID, 3 * HID, HID);
      gemm_tiled<false, true><<<g, 256, 0, stream>>>(
          xs + (size_t)OFF[t] * HID, Wk + HID, bk + HID,
          qagg + (size_t)OFF[t] * HID, NT[t], HID, 3 * HID, HID);
    }
    // alpha gather: a-dsts (ets 0,1), w-dsts (et 2), o-dsts (et 3)
    const float* Al = a_rel + (size_t)l * 4 * DD;
    const float* Ml = m_rel + (size_t)l * 4 * DD;
    const float* Pl = p_rel + (size_t)l * 4 * H;
    alpha_gather<<<(NA * H + 255) / 256, 256, 0, stream>>>(
        kv, qagg, rpAll + rpOff[0], ceAll, srcs[0], Al, Pl, alphaB,
        rpAll + rpOff[1], ceAll + E, srcs[1], Al + DD, Pl + H,
        alphaB + (size_t)E * H, 2, srcOffE[0], srcOffE[1], 0, NA, maxB, denB);
    alpha_gather<<<(NW * H + 255) / 256, 256, 0, stream>>>(
        kv, qagg, rpAll + rpOff[2], ceAll + 2 * (size_t)E, srcs[2], Al + 2 * DD,
        Pl + 2 * H, alphaB + 2 * (size_t)E * H, nullptr, nullptr, nullptr,
        nullptr, nullptr, nullptr, 1, srcOffE[2], 0, OFF[1], NW, maxB, denB);
    alpha_gather<<<(NO * H + 255) / 256, 256, 0, stream>>>(
        kv, qagg, rpAll + rpOff[3], ceAll + 3 * (size_t)E, srcs[3], Al + 3 * DD,
        Pl + 3 * H, alphaB + 3 * (size_t)E * H, nullptr, nullptr, nullptr,
        nullptr, nullptr, nullptr, 1, srcOffE[3], 0, OFF[2], NO, maxB, denB);
    // v -> kv (bf16), overwriting k
    for (int t = 0; t < 3; t++) {
      const float* Wk = W_kqv + (size_t)(l * 3 + t) * HID * 3 * HID;
      const float* bk = b_kqv + (size_t)(l * 3 + t) * 3 * HID;
      dim3 g((NT[t] + 63) / 64, 2);
      gemm_tiled<false, true><<<g, 256, 0, stream>>>(
          xs + (size_t)OFF[t] * HID, Wk + 2 * HID, bk + 2 * HID,
          kv + (size_t)OFF[t] * HID, NT[t], HID, 3 * HID, HID);
    }
    // agg gather -> qagg (bf16), overwriting q
    agg_gather<<<(NA * H + 255) / 256, 256, 0, stream>>>(
        kv, rpAll + rpOff[0], ceAll, srcs[0], Ml, alphaB, rpAll + rpOff[1],
        ceAll + E, srcs[1], Ml + DD, alphaB + (size_t)E * H, 2, srcOffE[0],
        srcOffE[1], 0, NA, maxB, denB, qagg);
    agg_gather<<<(NW * H + 255) / 256, 256, 0, stream>>>(
        kv, rpAll + rpOff[2], ceAll + 2 * (size_t)E, srcs[2], Ml + 2 * DD,
        alphaB + 2 * (size_t)E * H, nullptr, nullptr, nullptr, nullptr, nullptr,
        1, srcOffE[2], 0, OFF[1], NW, maxB, denB, qagg);
    agg_gather<<<(NO * H + 255) / 256, 256, 0, stream>>>(
        kv, rpAll + rpOff[3], ceAll + 3 * (size_t)E, srcs[3], Ml + 3 * DD,
        alphaB + 3 * (size_t)E * H, nullptr, nullptr, nullptr, nullptr, nullptr,
        1, srcOffE[3], 0, OFF[2], NO, maxB, denB, qagg);
    // fused: xs = relu(LN(g*(gelu(agg) @ W_o + b_o) + (1-g)*xs))
    for (int t = 0; t < 3; t++) {
      int blocks = (NT[t] + 63) / 64;
      gemm_wo_ln<<<blocks, 256, 0, stream>>>(
          qagg + (size_t)OFF[t] * HID, W_o + (size_t)(l * 3 + t) * HID * HID,
          b_o + (size_t)(l * 3 + t) * HID, xs + (size_t)OFF[t] * HID,
          skip_p + l * 3 + t, ln_g + (size_t)(l * 3 + t) * HID,
          ln_b + (size_t)(l * 3 + t) * HID, NT[t]);
    }
  }
  head_kernel<<<(NA + 3) / 4, 256, 0, stream>>>(xs, w_head, b_head, basep,
                                                (float*)d_out, NA);
}